// Round 1
// baseline (10550.197 us; speedup 1.0000x reference)
//
#include <hip/hip_runtime.h>
#include <math.h>

#define D_MODEL 1024
#define NH      16
#define DHEAD   64

// ---------------------------------------------------------------------------
// LayerNorm: one block per row of D_MODEL=1024, 256 threads, float4 per thread
// ---------------------------------------------------------------------------
__global__ __launch_bounds__(256) void ln_kernel(
    const float* __restrict__ X, const float* __restrict__ g,
    const float* __restrict__ bta, float* __restrict__ Y)
{
    __shared__ float red[8];
    const int row = blockIdx.x;
    const int tid = threadIdx.x;
    const float* x = X + (size_t)row * D_MODEL;

    float4 v = *(const float4*)&x[tid * 4];
    float s  = v.x + v.y + v.z + v.w;
    float sq = v.x * v.x + v.y * v.y + v.z * v.z + v.w * v.w;
#pragma unroll
    for (int o = 32; o > 0; o >>= 1) {
        s  += __shfl_down(s, o);
        sq += __shfl_down(sq, o);
    }
    if ((tid & 63) == 0) { red[tid >> 6] = s; red[4 + (tid >> 6)] = sq; }
    __syncthreads();
    const float ts = red[0] + red[1] + red[2] + red[3];
    const float tq = red[4] + red[5] + red[6] + red[7];
    const float mu   = ts * (1.0f / D_MODEL);
    const float var  = tq * (1.0f / D_MODEL) - mu * mu;
    const float rstd = 1.0f / sqrtf(var + 1e-5f);

    const float4 gv = *(const float4*)&g[tid * 4];
    const float4 bv = *(const float4*)&bta[tid * 4];
    float4 y;
    y.x = (v.x - mu) * rstd * gv.x + bv.x;
    y.y = (v.y - mu) * rstd * gv.y + bv.y;
    y.z = (v.z - mu) * rstd * gv.z + bv.z;
    y.w = (v.w - mu) * rstd * gv.w + bv.w;
    *(float4*)&Y[(size_t)row * D_MODEL + tid * 4] = y;
}

// ---------------------------------------------------------------------------
// FP32 GEMM: C[M,N] = A[M,K] @ B[K,N] (+bias) (+resid) (+exact GELU)
// BM=128, BN=64, BK=16, 256 threads, 8x4 register tile per thread.
// N and K must be multiples of 64/16 (true here); M guarded.
// ---------------------------------------------------------------------------
__device__ __forceinline__ float gelu_exact(float x) {
    return 0.5f * x * (1.0f + erff(x * 0.70710678118654752440f));
}

template <bool GELU>
__global__ __launch_bounds__(256) void gemm_kernel(
    const float* __restrict__ A, const float* __restrict__ B,
    const float* __restrict__ bias, const float* __restrict__ resid,
    float* __restrict__ C, int M, int N, int K)
{
    __shared__ float As[16][132];  // [k][m], padded
    __shared__ float Bs[16][64];   // [k][n]

    const int tid  = threadIdx.x;
    const int tx   = tid & 15;     // 16 col groups
    const int ty   = tid >> 4;     // 16 row groups
    const int row0 = blockIdx.y * 128;
    const int col0 = blockIdx.x * 64;

    // A tile load coords: 128 rows x 16 cols, 2 float4 per thread
    const int ar = tid >> 1;         // 0..127
    const int ac = (tid & 1) * 8;    // 0 or 8
    // B tile load coords: 16 rows x 64 cols, 1 float4 per thread
    const int br = tid >> 4;         // 0..15
    const int bc = (tid & 15) * 4;   // 0..60

    float acc[8][4];
#pragma unroll
    for (int i = 0; i < 8; ++i)
#pragma unroll
        for (int j = 0; j < 4; ++j) acc[i][j] = 0.0f;

    for (int kt = 0; kt < K; kt += 16) {
        float4 av0 = make_float4(0.f, 0.f, 0.f, 0.f);
        float4 av1 = make_float4(0.f, 0.f, 0.f, 0.f);
        if (row0 + ar < M) {
            const float* ap = &A[(size_t)(row0 + ar) * K + kt + ac];
            av0 = *(const float4*)&ap[0];
            av1 = *(const float4*)&ap[4];
        }
        const float4 bv = *(const float4*)&B[(size_t)(kt + br) * N + col0 + bc];

        __syncthreads();
        As[ac + 0][ar] = av0.x; As[ac + 1][ar] = av0.y;
        As[ac + 2][ar] = av0.z; As[ac + 3][ar] = av0.w;
        As[ac + 4][ar] = av1.x; As[ac + 5][ar] = av1.y;
        As[ac + 6][ar] = av1.z; As[ac + 7][ar] = av1.w;
        *(float4*)&Bs[br][bc] = bv;
        __syncthreads();

#pragma unroll
        for (int kk = 0; kk < 16; ++kk) {
            const float4 a0 = *(const float4*)&As[kk][ty * 4];
            const float4 a1 = *(const float4*)&As[kk][64 + ty * 4];
            const float4 b0 = *(const float4*)&Bs[kk][tx * 4];
            const float a[8] = {a0.x, a0.y, a0.z, a0.w, a1.x, a1.y, a1.z, a1.w};
            const float bb[4] = {b0.x, b0.y, b0.z, b0.w};
#pragma unroll
            for (int i = 0; i < 8; ++i)
#pragma unroll
                for (int j = 0; j < 4; ++j) acc[i][j] += a[i] * bb[j];
        }
    }

    // epilogue: float4 stores, rows ty*4+i and 64+ty*4+i, cols tx*4..+3
    const int c = col0 + tx * 4;
    float4 biasv = make_float4(0.f, 0.f, 0.f, 0.f);
    if (bias) biasv = *(const float4*)&bias[c];
#pragma unroll
    for (int ih = 0; ih < 2; ++ih) {
#pragma unroll
        for (int i = 0; i < 4; ++i) {
            const int r = row0 + ih * 64 + ty * 4 + i;
            if (r < M) {
                float4 v;
                v.x = acc[ih * 4 + i][0] + biasv.x;
                v.y = acc[ih * 4 + i][1] + biasv.y;
                v.z = acc[ih * 4 + i][2] + biasv.z;
                v.w = acc[ih * 4 + i][3] + biasv.w;
                if (resid) {
                    const float4 rv = *(const float4*)&resid[(size_t)r * N + c];
                    v.x += rv.x; v.y += rv.y; v.z += rv.z; v.w += rv.w;
                }
                if (GELU) {
                    v.x = gelu_exact(v.x); v.y = gelu_exact(v.y);
                    v.z = gelu_exact(v.z); v.w = gelu_exact(v.w);
                }
                *(float4*)&C[(size_t)r * N + c] = v;
            }
        }
    }
}

// ---------------------------------------------------------------------------
// Attention: one block (256 threads) per (q, h, b).  Scores kept in LDS.
// Q,K,V are [B*Sq,D] / [B*Sk,D] row-major with head h at columns h*64..h*64+63.
// Causal handled by truncating the k range (exact: mask=-1e9 => p=0 in fp32).
// scale = DH^-0.5 applied to scores (ref applies DH^-0.25 to q and k each).
// ---------------------------------------------------------------------------
template <bool CAUSAL>
__global__ __launch_bounds__(256) void attn_kernel(
    const float* __restrict__ Q, const float* __restrict__ K,
    const float* __restrict__ V, float* __restrict__ O,
    int Sq, int Sk, float scale)
{
    __shared__ float q_s[DHEAD];
    __shared__ float sc[1504];
    __shared__ float red[8];
    __shared__ float partial[4][DHEAD];

    const int q   = blockIdx.x;
    const int h   = blockIdx.y;
    const int b   = blockIdx.z;
    const int tid = threadIdx.x;

    const float* Qrow = Q + (size_t)(b * Sq + q) * D_MODEL + h * DHEAD;
    if (tid < DHEAD) q_s[tid] = Qrow[tid];
    __syncthreads();

    const int kmax = CAUSAL ? (q + 1) : Sk;

    // phase 1: scores
    float lmax = -INFINITY;
    for (int k = tid; k < kmax; k += 256) {
        const float* Krow = K + (size_t)(b * Sk + k) * D_MODEL + h * DHEAD;
        float s = 0.0f;
#pragma unroll
        for (int d4 = 0; d4 < 16; ++d4) {
            const float4 kv = *(const float4*)&Krow[d4 * 4];
            const float4 qv = *(const float4*)&q_s[d4 * 4];
            s += qv.x * kv.x + qv.y * kv.y + qv.z * kv.z + qv.w * kv.w;
        }
        s *= scale;
        sc[k] = s;
        lmax = fmaxf(lmax, s);
    }
#pragma unroll
    for (int o = 32; o > 0; o >>= 1) lmax = fmaxf(lmax, __shfl_down(lmax, o));
    if ((tid & 63) == 0) red[tid >> 6] = lmax;
    __syncthreads();
    const float m = fmaxf(fmaxf(red[0], red[1]), fmaxf(red[2], red[3]));

    // phase 2: exp + sum
    float lsum = 0.0f;
    for (int k = tid; k < kmax; k += 256) {
        const float p = expf(sc[k] - m);
        sc[k] = p;
        lsum += p;
    }
#pragma unroll
    for (int o = 32; o > 0; o >>= 1) lsum += __shfl_down(lsum, o);
    if ((tid & 63) == 0) red[4 + (tid >> 6)] = lsum;
    __syncthreads();
    const float l   = red[4] + red[5] + red[6] + red[7];
    const float inv = 1.0f / l;

    // phase 3: O = (P @ V) * inv ; 64 dims x 4 k-chunks
    const int d = tid & 63;
    const int cchunk = tid >> 6;
    float acc = 0.0f;
    for (int k = cchunk; k < kmax; k += 4) {
        acc += sc[k] * V[(size_t)(b * Sk + k) * D_MODEL + h * DHEAD + d];
    }
    partial[cchunk][d] = acc;
    __syncthreads();
    if (tid < DHEAD) {
        const float o =
            (partial[0][tid] + partial[1][tid] + partial[2][tid] + partial[3][tid]) * inv;
        O[(size_t)(b * Sq + q) * D_MODEL + h * DHEAD + tid] = o;
    }
}

// ---------------------------------------------------------------------------
// Orchestration
// ---------------------------------------------------------------------------
extern "C" void kernel_launch(void* const* d_in, const int* in_sizes, int n_in,
                              void* d_out, int out_size, void* d_ws, size_t ws_size,
                              hipStream_t stream)
{
    const int B = 4, S = 1024, T = 1500, DFF = 4096;
    const int MS = B * S;   // 4096
    const int MT = B * T;   // 6000

    const float* x          = (const float*)d_in[0];
    const float* xa         = (const float*)d_in[1];
    // d_in[2] = mask (unused: causal handled analytically)
    const float* attn_ln_g  = (const float*)d_in[3];
    const float* attn_ln_b  = (const float*)d_in[4];
    const float* sa_wq      = (const float*)d_in[5];
    const float* sa_bq      = (const float*)d_in[6];
    const float* sa_wk      = (const float*)d_in[7];
    const float* sa_wv      = (const float*)d_in[8];
    const float* sa_bv      = (const float*)d_in[9];
    const float* sa_wo      = (const float*)d_in[10];
    const float* sa_bo      = (const float*)d_in[11];
    const float* cross_ln_g = (const float*)d_in[12];
    const float* cross_ln_b = (const float*)d_in[13];
    const float* ca_wq      = (const float*)d_in[14];
    const float* ca_bq      = (const float*)d_in[15];
    const float* ca_wk      = (const float*)d_in[16];
    const float* ca_wv      = (const float*)d_in[17];
    const float* ca_bv      = (const float*)d_in[18];
    const float* ca_wo      = (const float*)d_in[19];
    const float* ca_bo      = (const float*)d_in[20];
    const float* mlp_ln_g   = (const float*)d_in[21];
    const float* mlp_ln_b   = (const float*)d_in[22];
    const float* mlp_w1     = (const float*)d_in[23];
    const float* mlp_b1     = (const float*)d_in[24];
    const float* mlp_w2     = (const float*)d_in[25];
    const float* mlp_b2     = (const float*)d_in[26];

    float* ws = (float*)d_ws;
    size_t off = 0;
    float* lnb = ws + off; off += (size_t)MS * D_MODEL;           // 4096x1024
    float* r1  = ws + off; off += (size_t)MS * D_MODEL;           // residual stream
    const size_t qoff = off;
    float* qb  = ws + off; off += (size_t)MS * D_MODEL;
    float* kb  = ws + off; off += (size_t)MT * D_MODEL;
    float* vb  = ws + off; off += (size_t)MT * D_MODEL;
    float* ab  = ws + off; off += (size_t)MS * D_MODEL;
    float* hb  = ws + qoff;  // reuse qb..ab region for 4096x4096 hidden

    const float scale = 0.125f;  // DH^-0.5 = 64^-0.5

    auto gemm = [&](const float* A, const float* Bm, const float* bias,
                    const float* resid, float* C, int M, int N, int K, bool gelu) {
        dim3 grid(N / 64, (M + 127) / 128);
        if (gelu)
            gemm_kernel<true><<<grid, 256, 0, stream>>>(A, Bm, bias, resid, C, M, N, K);
        else
            gemm_kernel<false><<<grid, 256, 0, stream>>>(A, Bm, bias, resid, C, M, N, K);
    };

    // ---- self-attention block ----
    ln_kernel<<<MS, 256, 0, stream>>>(x, attn_ln_g, attn_ln_b, lnb);
    gemm(lnb, sa_wq, sa_bq, nullptr, qb, MS, D_MODEL, D_MODEL, false);
    gemm(lnb, sa_wk, nullptr, nullptr, kb, MS, D_MODEL, D_MODEL, false);
    gemm(lnb, sa_wv, sa_bv, nullptr, vb, MS, D_MODEL, D_MODEL, false);
    attn_kernel<true><<<dim3(S, NH, B), 256, 0, stream>>>(qb, kb, vb, ab, S, S, scale);
    gemm(ab, sa_wo, sa_bo, x, r1, MS, D_MODEL, D_MODEL, false);

    // ---- cross-attention block ----
    ln_kernel<<<MS, 256, 0, stream>>>(r1, cross_ln_g, cross_ln_b, lnb);
    gemm(lnb, ca_wq, ca_bq, nullptr, qb, MS, D_MODEL, D_MODEL, false);
    gemm(xa, ca_wk, nullptr, nullptr, kb, MT, D_MODEL, D_MODEL, false);
    gemm(xa, ca_wv, ca_bv, nullptr, vb, MT, D_MODEL, D_MODEL, false);
    attn_kernel<false><<<dim3(S, NH, B), 256, 0, stream>>>(qb, kb, vb, ab, S, T, scale);
    gemm(ab, ca_wo, ca_bo, r1, r1, MS, D_MODEL, D_MODEL, false);

    // ---- MLP block ----
    ln_kernel<<<MS, 256, 0, stream>>>(r1, mlp_ln_g, mlp_ln_b, lnb);
    gemm(lnb, mlp_w1, mlp_b1, nullptr, hb, MS, DFF, D_MODEL, true);     // + exact GELU
    gemm(hb, mlp_w2, mlp_b2, r1, (float*)d_out, MS, D_MODEL, DFF, false);
}

// Round 4
// 3205.387 us; speedup vs baseline: 3.2914x; 3.2914x over previous
//
#include <hip/hip_runtime.h>
#include <math.h>

#define D_MODEL 1024
#define NH      16
#define DHEAD   64

// ---------------------------------------------------------------------------
// LayerNorm: one block per row of D_MODEL=1024, 256 threads, float4 per thread
// ---------------------------------------------------------------------------
__global__ __launch_bounds__(256) void ln_kernel(
    const float* __restrict__ X, const float* __restrict__ g,
    const float* __restrict__ bta, float* __restrict__ Y)
{
    __shared__ float red[8];
    const int row = blockIdx.x;
    const int tid = threadIdx.x;
    const float* x = X + (size_t)row * D_MODEL;

    float4 v = *(const float4*)&x[tid * 4];
    float s  = v.x + v.y + v.z + v.w;
    float sq = v.x * v.x + v.y * v.y + v.z * v.z + v.w * v.w;
#pragma unroll
    for (int o = 32; o > 0; o >>= 1) {
        s  += __shfl_down(s, o);
        sq += __shfl_down(sq, o);
    }
    if ((tid & 63) == 0) { red[tid >> 6] = s; red[4 + (tid >> 6)] = sq; }
    __syncthreads();
    const float ts = red[0] + red[1] + red[2] + red[3];
    const float tq = red[4] + red[5] + red[6] + red[7];
    const float mu   = ts * (1.0f / D_MODEL);
    const float var  = tq * (1.0f / D_MODEL) - mu * mu;
    const float rstd = 1.0f / sqrtf(var + 1e-5f);

    const float4 gv = *(const float4*)&g[tid * 4];
    const float4 bv = *(const float4*)&bta[tid * 4];
    float4 y;
    y.x = (v.x - mu) * rstd * gv.x + bv.x;
    y.y = (v.y - mu) * rstd * gv.y + bv.y;
    y.z = (v.z - mu) * rstd * gv.z + bv.z;
    y.w = (v.w - mu) * rstd * gv.w + bv.w;
    *(float4*)&Y[(size_t)row * D_MODEL + tid * 4] = y;
}

// ---------------------------------------------------------------------------
// FP32 GEMM: C[M,N] = A[M,K] @ B[K,N] (+bias) (+resid) (+exact GELU)
// BM=128, BN=64, BK=16, 256 threads, 8x4 register tile per thread.
// ---------------------------------------------------------------------------
__device__ __forceinline__ float gelu_exact(float x) {
    return 0.5f * x * (1.0f + erff(x * 0.70710678118654752440f));
}

template <bool GELU>
__global__ __launch_bounds__(256) void gemm_kernel(
    const float* __restrict__ A, const float* __restrict__ B,
    const float* __restrict__ bias, const float* __restrict__ resid,
    float* __restrict__ C, int M, int N, int K)
{
    __shared__ float As[16][132];  // [k][m], padded
    __shared__ float Bs[16][64];   // [k][n]

    const int tid  = threadIdx.x;
    const int tx   = tid & 15;     // 16 col groups
    const int ty   = tid >> 4;     // 16 row groups
    const int row0 = blockIdx.y * 128;
    const int col0 = blockIdx.x * 64;

    const int ar = tid >> 1;         // 0..127
    const int ac = (tid & 1) * 8;    // 0 or 8
    const int br = tid >> 4;         // 0..15
    const int bc = (tid & 15) * 4;   // 0..60

    float acc[8][4];
#pragma unroll
    for (int i = 0; i < 8; ++i)
#pragma unroll
        for (int j = 0; j < 4; ++j) acc[i][j] = 0.0f;

    for (int kt = 0; kt < K; kt += 16) {
        float4 av0 = make_float4(0.f, 0.f, 0.f, 0.f);
        float4 av1 = make_float4(0.f, 0.f, 0.f, 0.f);
        if (row0 + ar < M) {
            const float* ap = &A[(size_t)(row0 + ar) * K + kt + ac];
            av0 = *(const float4*)&ap[0];
            av1 = *(const float4*)&ap[4];
        }
        const float4 bv = *(const float4*)&B[(size_t)(kt + br) * N + col0 + bc];

        __syncthreads();
        As[ac + 0][ar] = av0.x; As[ac + 1][ar] = av0.y;
        As[ac + 2][ar] = av0.z; As[ac + 3][ar] = av0.w;
        As[ac + 4][ar] = av1.x; As[ac + 5][ar] = av1.y;
        As[ac + 6][ar] = av1.z; As[ac + 7][ar] = av1.w;
        *(float4*)&Bs[br][bc] = bv;
        __syncthreads();

#pragma unroll
        for (int kk = 0; kk < 16; ++kk) {
            const float4 a0 = *(const float4*)&As[kk][ty * 4];
            const float4 a1 = *(const float4*)&As[kk][64 + ty * 4];
            const float4 b0 = *(const float4*)&Bs[kk][tx * 4];
            const float a[8] = {a0.x, a0.y, a0.z, a0.w, a1.x, a1.y, a1.z, a1.w};
            const float bb[4] = {b0.x, b0.y, b0.z, b0.w};
#pragma unroll
            for (int i = 0; i < 8; ++i)
#pragma unroll
                for (int j = 0; j < 4; ++j) acc[i][j] += a[i] * bb[j];
        }
    }

    const int c = col0 + tx * 4;
    float4 biasv = make_float4(0.f, 0.f, 0.f, 0.f);
    if (bias) biasv = *(const float4*)&bias[c];
#pragma unroll
    for (int ih = 0; ih < 2; ++ih) {
#pragma unroll
        for (int i = 0; i < 4; ++i) {
            const int r = row0 + ih * 64 + ty * 4 + i;
            if (r < M) {
                float4 v;
                v.x = acc[ih * 4 + i][0] + biasv.x;
                v.y = acc[ih * 4 + i][1] + biasv.y;
                v.z = acc[ih * 4 + i][2] + biasv.z;
                v.w = acc[ih * 4 + i][3] + biasv.w;
                if (resid) {
                    const float4 rv = *(const float4*)&resid[(size_t)r * N + c];
                    v.x += rv.x; v.y += rv.y; v.z += rv.z; v.w += rv.w;
                }
                if (GELU) {
                    v.x = gelu_exact(v.x); v.y = gelu_exact(v.y);
                    v.z = gelu_exact(v.z); v.w = gelu_exact(v.w);
                }
                *(float4*)&C[(size_t)r * N + c] = v;
            }
        }
    }
}

// ---------------------------------------------------------------------------
// Flash attention (fp32): one block per (q-tile of 64, h, b). 256 threads.
// Each thread owns a 4x4 tile of the 64x64 score block: rows ty*4.., cols tx*4..
// K stored transposed in LDS (Kst[d][j]); P aliases Kst (barrier-separated).
// Online softmax with running (m,l) per row, shfl_xor reduce over 16 tx lanes.
// Causal: skip k-tiles > qt, mask diagonal tile. Exactly matches -1e9 mask
// semantics in fp32 (exp underflows to 0).
// ---------------------------------------------------------------------------
template <bool CAUSAL>
__global__ __launch_bounds__(256) void fattn_kernel(
    const float* __restrict__ Q, const float* __restrict__ K,
    const float* __restrict__ V, float* __restrict__ O,
    int Sq, int Sk)
{
    __shared__ float Qs[64][68];
    __shared__ float KPs[64][68];   // K-transposed during QK; P during PV
    __shared__ float Vs[64][64];

    const int qt  = blockIdx.x;
    const int h   = blockIdx.y;
    const int b   = blockIdx.z;
    const int tid = threadIdx.x;
    const int tx  = tid & 15;
    const int ty  = tid >> 4;

    // cooperative load coords: 64 rows x 64 cols, each thread 16 consecutive
    const int lr = tid >> 2;         // 0..63
    const int lc = (tid & 3) * 16;   // 0,16,32,48

    // ---- load Q tile (rows qt*64.., head h) ----
    {
        const float* qp = Q + ((size_t)(b * Sq + qt * 64 + lr)) * D_MODEL + h * DHEAD + lc;
#pragma unroll
        for (int u = 0; u < 4; ++u)
            *(float4*)&Qs[lr][lc + u * 4] = *(const float4*)&qp[u * 4];
    }

    float m_run[4], l_run[4], o[4][4];
#pragma unroll
    for (int i = 0; i < 4; ++i) {
        m_run[i] = -INFINITY;
        l_run[i] = 0.0f;
#pragma unroll
        for (int c = 0; c < 4; ++c) o[i][c] = 0.0f;
    }

    const int ig0 = qt * 64 + ty * 4;
    const int nkt = CAUSAL ? (qt + 1) : ((Sk + 63) >> 6);

    for (int kt = 0; kt < nkt; ++kt) {
        __syncthreads();  // prev PV done before overwriting KPs/Vs
        {
            const int kr = kt * 64 + lr;
            if (!CAUSAL && kr >= Sk) {
#pragma unroll
                for (int u = 0; u < 16; ++u) KPs[lc + u][lr] = 0.0f;
#pragma unroll
                for (int u = 0; u < 4; ++u)
                    *(float4*)&Vs[lr][lc + u * 4] = make_float4(0.f, 0.f, 0.f, 0.f);
            } else {
                const float* kp = K + ((size_t)(b * Sk + kr)) * D_MODEL + h * DHEAD + lc;
                const float* vp = V + ((size_t)(b * Sk + kr)) * D_MODEL + h * DHEAD + lc;
#pragma unroll
                for (int u = 0; u < 4; ++u) {
                    const float4 kv = *(const float4*)&kp[u * 4];
                    KPs[lc + u * 4 + 0][lr] = kv.x;
                    KPs[lc + u * 4 + 1][lr] = kv.y;
                    KPs[lc + u * 4 + 2][lr] = kv.z;
                    KPs[lc + u * 4 + 3][lr] = kv.w;
                    *(float4*)&Vs[lr][lc + u * 4] = *(const float4*)&vp[u * 4];
                }
            }
        }
        __syncthreads();

        // ---- S = (Q @ K^T) * 0.125 ----
        float s[4][4];
#pragma unroll
        for (int i = 0; i < 4; ++i)
#pragma unroll
            for (int j = 0; j < 4; ++j) s[i][j] = 0.0f;

#pragma unroll
        for (int d4 = 0; d4 < 16; ++d4) {
            float4 qv[4], kv[4];
#pragma unroll
            for (int i = 0; i < 4; ++i) qv[i] = *(const float4*)&Qs[ty * 4 + i][d4 * 4];
#pragma unroll
            for (int dd = 0; dd < 4; ++dd) kv[dd] = *(const float4*)&KPs[d4 * 4 + dd][tx * 4];
#pragma unroll
            for (int i = 0; i < 4; ++i) {
                const float q0 = qv[i].x, q1 = qv[i].y, q2 = qv[i].z, q3 = qv[i].w;
#pragma unroll
                for (int j = 0; j < 4; ++j) {
                    const float k0 = (&kv[0].x)[j], k1 = (&kv[1].x)[j],
                                k2 = (&kv[2].x)[j], k3 = (&kv[3].x)[j];
                    s[i][j] += q0 * k0 + q1 * k1 + q2 * k2 + q3 * k3;
                }
            }
        }

        const int jg0 = kt * 64 + tx * 4;
#pragma unroll
        for (int i = 0; i < 4; ++i)
#pragma unroll
            for (int j = 0; j < 4; ++j) s[i][j] *= 0.125f;

        if (CAUSAL && kt == qt) {
#pragma unroll
            for (int i = 0; i < 4; ++i)
#pragma unroll
                for (int j = 0; j < 4; ++j)
                    if (jg0 + j > ig0 + i) s[i][j] = -INFINITY;
        }
        if (!CAUSAL && kt == nkt - 1) {
#pragma unroll
            for (int i = 0; i < 4; ++i)
#pragma unroll
                for (int j = 0; j < 4; ++j)
                    if (jg0 + j >= Sk) s[i][j] = -INFINITY;
        }

        __syncthreads();  // all done reading KPs(=Kst) before P overwrite

        // ---- online softmax ----
        float mt[4], sf[4], rs[4];
#pragma unroll
        for (int i = 0; i < 4; ++i)
            mt[i] = fmaxf(fmaxf(s[i][0], s[i][1]), fmaxf(s[i][2], s[i][3]));
#pragma unroll
        for (int off = 1; off < 16; off <<= 1)
#pragma unroll
            for (int i = 0; i < 4; ++i) mt[i] = fmaxf(mt[i], __shfl_xor(mt[i], off));
#pragma unroll
        for (int i = 0; i < 4; ++i) {
            const float mn = fmaxf(m_run[i], mt[i]);
            sf[i] = expf(m_run[i] - mn);
            m_run[i] = mn;
            rs[i] = 0.0f;
#pragma unroll
            for (int j = 0; j < 4; ++j) {
                const float p = expf(s[i][j] - mn);
                s[i][j] = p;
                rs[i] += p;
            }
        }
#pragma unroll
        for (int off = 1; off < 16; off <<= 1)
#pragma unroll
            for (int i = 0; i < 4; ++i) rs[i] += __shfl_xor(rs[i], off);
#pragma unroll
        for (int i = 0; i < 4; ++i) {
            l_run[i] = l_run[i] * sf[i] + rs[i];
            *(float4*)&KPs[ty * 4 + i][tx * 4] = make_float4(s[i][0], s[i][1], s[i][2], s[i][3]);
#pragma unroll
            for (int c = 0; c < 4; ++c) o[i][c] *= sf[i];
        }
        __syncthreads();  // P visible to all

        // ---- O += P @ V ----  (thread: rows ty*4.., dims tx*4..)
#pragma unroll
        for (int j4 = 0; j4 < 16; ++j4) {
            float4 pv[4], vr[4];
#pragma unroll
            for (int i = 0; i < 4; ++i) pv[i] = *(const float4*)&KPs[ty * 4 + i][j4 * 4];
#pragma unroll
            for (int jj = 0; jj < 4; ++jj) vr[jj] = *(const float4*)&Vs[j4 * 4 + jj][tx * 4];
#pragma unroll
            for (int i = 0; i < 4; ++i) {
#pragma unroll
                for (int c = 0; c < 4; ++c) {
                    o[i][c] += pv[i].x * (&vr[0].x)[c] + pv[i].y * (&vr[1].x)[c]
                             + pv[i].z * (&vr[2].x)[c] + pv[i].w * (&vr[3].x)[c];
                }
            }
        }
    }

    // ---- epilogue ----
#pragma unroll
    for (int i = 0; i < 4; ++i) {
        const float inv = 1.0f / l_run[i];
        const size_t r = (size_t)(b * Sq + qt * 64 + ty * 4 + i);
        float4 v;
        v.x = o[i][0] * inv; v.y = o[i][1] * inv;
        v.z = o[i][2] * inv; v.w = o[i][3] * inv;
        *(float4*)&O[r * D_MODEL + h * DHEAD + tx * 4] = v;
    }
}

// ---------------------------------------------------------------------------
// Orchestration
// ---------------------------------------------------------------------------
extern "C" void kernel_launch(void* const* d_in, const int* in_sizes, int n_in,
                              void* d_out, int out_size, void* d_ws, size_t ws_size,
                              hipStream_t stream)
{
    const int B = 4, S = 1024, T = 1500, DFF = 4096;
    const int MS = B * S;   // 4096
    const int MT = B * T;   // 6000

    const float* x          = (const float*)d_in[0];
    const float* xa         = (const float*)d_in[1];
    const float* attn_ln_g  = (const float*)d_in[3];
    const float* attn_ln_b  = (const float*)d_in[4];
    const float* sa_wq      = (const float*)d_in[5];
    const float* sa_bq      = (const float*)d_in[6];
    const float* sa_wk      = (const float*)d_in[7];
    const float* sa_wv      = (const float*)d_in[8];
    const float* sa_bv      = (const float*)d_in[9];
    const float* sa_wo      = (const float*)d_in[10];
    const float* sa_bo      = (const float*)d_in[11];
    const float* cross_ln_g = (const float*)d_in[12];
    const float* cross_ln_b = (const float*)d_in[13];
    const float* ca_wq      = (const float*)d_in[14];
    const float* ca_bq      = (const float*)d_in[15];
    const float* ca_wk      = (const float*)d_in[16];
    const float* ca_wv      = (const float*)d_in[17];
    const float* ca_bv      = (const float*)d_in[18];
    const float* ca_wo      = (const float*)d_in[19];
    const float* ca_bo      = (const float*)d_in[20];
    const float* mlp_ln_g   = (const float*)d_in[21];
    const float* mlp_ln_b   = (const float*)d_in[22];
    const float* mlp_w1     = (const float*)d_in[23];
    const float* mlp_b1     = (const float*)d_in[24];
    const float* mlp_w2     = (const float*)d_in[25];
    const float* mlp_b2     = (const float*)d_in[26];

    float* ws = (float*)d_ws;
    size_t off = 0;
    float* lnb = ws + off; off += (size_t)MS * D_MODEL;
    float* r1  = ws + off; off += (size_t)MS * D_MODEL;
    const size_t qoff = off;
    float* qb  = ws + off; off += (size_t)MS * D_MODEL;
    float* kb  = ws + off; off += (size_t)MT * D_MODEL;
    float* vb  = ws + off; off += (size_t)MT * D_MODEL;
    float* ab  = ws + off; off += (size_t)MS * D_MODEL;
    float* hb  = ws + qoff;  // reuse qb..ab region for 4096x4096 hidden

    auto gemm = [&](const float* A, const float* Bm, const float* bias,
                    const float* resid, float* C, int M, int N, int K, bool gelu) {
        dim3 grid(N / 64, (M + 127) / 128);
        if (gelu)
            gemm_kernel<true><<<grid, 256, 0, stream>>>(A, Bm, bias, resid, C, M, N, K);
        else
            gemm_kernel<false><<<grid, 256, 0, stream>>>(A, Bm, bias, resid, C, M, N, K);
    };

    // ---- self-attention block ----
    ln_kernel<<<MS, 256, 0, stream>>>(x, attn_ln_g, attn_ln_b, lnb);
    gemm(lnb, sa_wq, sa_bq, nullptr, qb, MS, D_MODEL, D_MODEL, false);
    gemm(lnb, sa_wk, nullptr, nullptr, kb, MS, D_MODEL, D_MODEL, false);
    gemm(lnb, sa_wv, sa_bv, nullptr, vb, MS, D_MODEL, D_MODEL, false);
    fattn_kernel<true><<<dim3(S / 64, NH, B), 256, 0, stream>>>(qb, kb, vb, ab, S, S);
    gemm(ab, sa_wo, sa_bo, x, r1, MS, D_MODEL, D_MODEL, false);

    // ---- cross-attention block ----
    ln_kernel<<<MS, 256, 0, stream>>>(r1, cross_ln_g, cross_ln_b, lnb);
    gemm(lnb, ca_wq, ca_bq, nullptr, qb, MS, D_MODEL, D_MODEL, false);
    gemm(xa, ca_wk, nullptr, nullptr, kb, MT, D_MODEL, D_MODEL, false);
    gemm(xa, ca_wv, ca_bv, nullptr, vb, MT, D_MODEL, D_MODEL, false);
    fattn_kernel<false><<<dim3(S / 64, NH, B), 256, 0, stream>>>(qb, kb, vb, ab, S, T);
    gemm(ab, ca_wo, ca_bo, r1, r1, MS, D_MODEL, D_MODEL, false);

    // ---- MLP block ----
    ln_kernel<<<MS, 256, 0, stream>>>(r1, mlp_ln_g, mlp_ln_b, lnb);
    gemm(lnb, mlp_w1, mlp_b1, nullptr, hb, MS, DFF, D_MODEL, true);
    gemm(hb, mlp_w2, mlp_b2, r1, (float*)d_out, MS, D_MODEL, DFF, false);
}

// Round 9
// 1754.828 us; speedup vs baseline: 6.0121x; 1.8266x over previous
//
#include <hip/hip_runtime.h>
#include <math.h>

#define D_MODEL 1024
#define NH      16
#define DHEAD   64
#define LDK     40   // padded LDS K-stride (bf16 elems) -> 80B rows, ~2-way banks

typedef __attribute__((ext_vector_type(8))) short bf16x8;
typedef __attribute__((ext_vector_type(4))) float f32x4;

__device__ __forceinline__ unsigned short f2b(float f) {
    union { float f; unsigned u; } v; v.f = f;
    unsigned r = v.u + 0x7FFFu + ((v.u >> 16) & 1u);   // RNE
    return (unsigned short)(r >> 16);
}
__device__ __forceinline__ float b2f(unsigned u) {
    union { unsigned u; float f; } v; v.u = u << 16;
    return v.f;
}
__device__ __forceinline__ void b8tof(const uint4 v, float* f) {
    f[0]=b2f(v.x & 0xffffu); f[1]=b2f(v.x >> 16);
    f[2]=b2f(v.y & 0xffffu); f[3]=b2f(v.y >> 16);
    f[4]=b2f(v.z & 0xffffu); f[5]=b2f(v.z >> 16);
    f[6]=b2f(v.w & 0xffffu); f[7]=b2f(v.w >> 16);
}
__device__ __forceinline__ float gelu_exact(float x) {
    return 0.5f * x * (1.0f + erff(x * 0.70710678118654752440f));
}

// ---------------------------------------------------------------------------
// LayerNorm: fp32 in, bf16 out (feeds MFMA GEMMs)
// ---------------------------------------------------------------------------
__global__ __launch_bounds__(256) void ln_kernel(
    const float* __restrict__ X, const float* __restrict__ g,
    const float* __restrict__ bta, unsigned short* __restrict__ Y)
{
    __shared__ float red[8];
    const int row = blockIdx.x;
    const int tid = threadIdx.x;
    const float* x = X + (size_t)row * D_MODEL;

    float4 v = *(const float4*)&x[tid * 4];
    float s  = v.x + v.y + v.z + v.w;
    float sq = v.x * v.x + v.y * v.y + v.z * v.z + v.w * v.w;
#pragma unroll
    for (int o = 32; o > 0; o >>= 1) {
        s  += __shfl_down(s, o);
        sq += __shfl_down(sq, o);
    }
    if ((tid & 63) == 0) { red[tid >> 6] = s; red[4 + (tid >> 6)] = sq; }
    __syncthreads();
    const float ts = red[0] + red[1] + red[2] + red[3];
    const float tq = red[4] + red[5] + red[6] + red[7];
    const float mu   = ts * (1.0f / D_MODEL);
    const float var  = tq * (1.0f / D_MODEL) - mu * mu;
    const float rstd = 1.0f / sqrtf(var + 1e-5f);

    const float4 gv = *(const float4*)&g[tid * 4];
    const float4 bv = *(const float4*)&bta[tid * 4];
    ushort4 y;
    y.x = f2b((v.x - mu) * rstd * gv.x + bv.x);
    y.y = f2b((v.y - mu) * rstd * gv.y + bv.y);
    y.z = f2b((v.z - mu) * rstd * gv.z + bv.z);
    y.w = f2b((v.w - mu) * rstd * gv.w + bv.w);
    *(ushort4*)&Y[(size_t)row * D_MODEL + tid * 4] = y;
}

// ---------------------------------------------------------------------------
// fp32 -> bf16 elementwise (for xa)
// ---------------------------------------------------------------------------
__global__ __launch_bounds__(256) void f2b_kernel(
    const float* __restrict__ in, unsigned short* __restrict__ out, int n4)
{
    int i = blockIdx.x * blockDim.x + threadIdx.x;
    for (; i < n4; i += gridDim.x * blockDim.x) {
        float4 v = ((const float4*)in)[i];
        ushort4 o; o.x = f2b(v.x); o.y = f2b(v.y); o.z = f2b(v.z); o.w = f2b(v.w);
        ((ushort4*)out)[i] = o;
    }
}

// ---------------------------------------------------------------------------
// Weight transpose+convert: W[K][N] fp32 -> Wt[N][K] bf16
// ---------------------------------------------------------------------------
__global__ __launch_bounds__(256) void wtrans_kernel(
    const float* __restrict__ W, unsigned short* __restrict__ Wt, int K, int N)
{
    __shared__ float t[32][33];
    const int n0 = blockIdx.x * 32, k0 = blockIdx.y * 32;
    const int tx = threadIdx.x, ty = threadIdx.y;  // (32, 8)
#pragma unroll
    for (int i = 0; i < 4; ++i)
        t[ty + i * 8][tx] = W[(size_t)(k0 + ty + i * 8) * N + n0 + tx];
    __syncthreads();
#pragma unroll
    for (int i = 0; i < 4; ++i)
        Wt[(size_t)(n0 + ty + i * 8) * K + k0 + tx] = f2b(t[tx][ty + i * 8]);
}

// ---------------------------------------------------------------------------
// BF16 MFMA GEMM: C[M,N] = A[M,K] @ Wt[N,K]^T (+bias)(+resid)(+GELU)
// 128x128 tile, BK=32, 256 thr = 4 waves (2x2 of 64x64), 16x16x32 MFMA.
// A,Wt bf16 row-major; A buffer rows padded to x128 (poison-safe, finite).
// ---------------------------------------------------------------------------
template <bool GELU, bool OBF16>
__global__ __launch_bounds__(256) void mfma_gemm(
    const unsigned short* __restrict__ A, const unsigned short* __restrict__ Wt,
    const float* __restrict__ bias, const float* __restrict__ resid,
    void* __restrict__ C, int M, int N, int K)
{
    __shared__ unsigned short As[128 * LDK];
    __shared__ unsigned short Bs[128 * LDK];

    const int tid  = threadIdx.x;
    const int row0 = blockIdx.y * 128;
    const int col0 = blockIdx.x * 128;
    const int l = tid & 63, w = tid >> 6;
    const int wr = (w >> 1) * 64, wc = (w & 1) * 64;
    const int sr = tid >> 1;            // staging row 0..127
    const int sc = (tid & 1) * 16;      // staging col 0/16

    f32x4 acc[4][4] = {};

    const unsigned short* Ap = A  + (size_t)(row0 + sr) * K + sc;
    const unsigned short* Bp = Wt + (size_t)(col0 + sr) * K + sc;

    uint4 a0 = *(const uint4*)(Ap);     uint4 a1 = *(const uint4*)(Ap + 8);
    uint4 b0 = *(const uint4*)(Bp);     uint4 b1 = *(const uint4*)(Bp + 8);

    const int fr = l & 15, fk = (l >> 4) * 8;

    for (int kt = 0; kt < K; kt += 32) {
        __syncthreads();
        *(uint4*)&As[sr * LDK + sc]     = a0;
        *(uint4*)&As[sr * LDK + sc + 8] = a1;
        *(uint4*)&Bs[sr * LDK + sc]     = b0;
        *(uint4*)&Bs[sr * LDK + sc + 8] = b1;
        __syncthreads();
        if (kt + 32 < K) {   // prefetch next K-tile (hides HBM latency)
            a0 = *(const uint4*)(Ap + kt + 32); a1 = *(const uint4*)(Ap + kt + 40);
            b0 = *(const uint4*)(Bp + kt + 32); b1 = *(const uint4*)(Bp + kt + 40);
        }
        bf16x8 af[4], bf[4];
#pragma unroll
        for (int m = 0; m < 4; ++m)
            af[m] = *(const bf16x8*)&As[(wr + m * 16 + fr) * LDK + fk];
#pragma unroll
        for (int n = 0; n < 4; ++n)
            bf[n] = *(const bf16x8*)&Bs[(wc + n * 16 + fr) * LDK + fk];
#pragma unroll
        for (int m = 0; m < 4; ++m)
#pragma unroll
            for (int n = 0; n < 4; ++n)
                acc[m][n] = __builtin_amdgcn_mfma_f32_16x16x32_bf16(
                    af[m], bf[n], acc[m][n], 0, 0, 0);
    }

    // epilogue: C/D layout col=l&15, row=(l>>4)*4+i  [verified m89]
    const int fq = l >> 4;
#pragma unroll
    for (int m = 0; m < 4; ++m) {
#pragma unroll
        for (int i = 0; i < 4; ++i) {
            const int r = row0 + wr + m * 16 + fq * 4 + i;
            if (r < M) {
#pragma unroll
                for (int n = 0; n < 4; ++n) {
                    const int c = col0 + wc + n * 16 + fr;
                    float v = acc[m][n][i];
                    if (bias)  v += bias[c];
                    if (resid) v += resid[(size_t)r * N + c];
                    if (GELU)  v = gelu_exact(v);
                    if (OBF16) ((unsigned short*)C)[(size_t)r * N + c] = f2b(v);
                    else       ((float*)C)[(size_t)r * N + c] = v;
                }
            }
        }
    }
}

// ---------------------------------------------------------------------------
// Flash attention: bf16 Q/K/V in, bf16 O out; fp32 math inside (unchanged).
// One block per (q-tile 64, h, b), 256 threads, 4x4 score tile per thread.
// ---------------------------------------------------------------------------
template <bool CAUSAL>
__global__ __launch_bounds__(256) void fattn_kernel(
    const unsigned short* __restrict__ Q, const unsigned short* __restrict__ K,
    const unsigned short* __restrict__ V, unsigned short* __restrict__ O,
    int Sq, int Sk)
{
    __shared__ float Qs[64][68];
    __shared__ float KPs[64][68];   // K-transposed during QK; P during PV
    __shared__ float Vs[64][64];

    const int qt  = blockIdx.x;
    const int h   = blockIdx.y;
    const int b   = blockIdx.z;
    const int tid = threadIdx.x;
    const int tx  = tid & 15;
    const int ty  = tid >> 4;

    const int lr = tid >> 2;         // 0..63
    const int lc = (tid & 3) * 16;   // 0,16,32,48

    {
        const unsigned short* qp =
            Q + ((size_t)(b * Sq + qt * 64 + lr)) * D_MODEL + h * DHEAD + lc;
        float f[8];
        uint4 v1 = *(const uint4*)qp;       b8tof(v1, f);
#pragma unroll
        for (int u = 0; u < 8; ++u) Qs[lr][lc + u] = f[u];
        uint4 v2 = *(const uint4*)(qp + 8); b8tof(v2, f);
#pragma unroll
        for (int u = 0; u < 8; ++u) Qs[lr][lc + 8 + u] = f[u];
    }

    float m_run[4], l_run[4], oacc[4][4];
#pragma unroll
    for (int i = 0; i < 4; ++i) {
        m_run[i] = -INFINITY;
        l_run[i] = 0.0f;
#pragma unroll
        for (int c = 0; c < 4; ++c) oacc[i][c] = 0.0f;
    }

    const int ig0 = qt * 64 + ty * 4;
    const int nkt = CAUSAL ? (qt + 1) : ((Sk + 63) >> 6);

    for (int kt = 0; kt < nkt; ++kt) {
        __syncthreads();
        {
            const int kr = kt * 64 + lr;
            if (!CAUSAL && kr >= Sk) {
#pragma unroll
                for (int u = 0; u < 16; ++u) KPs[lc + u][lr] = 0.0f;
#pragma unroll
                for (int u = 0; u < 16; ++u) Vs[lr][lc + u] = 0.0f;
            } else {
                const unsigned short* kp =
                    K + ((size_t)(b * Sk + kr)) * D_MODEL + h * DHEAD + lc;
                const unsigned short* vp =
                    V + ((size_t)(b * Sk + kr)) * D_MODEL + h * DHEAD + lc;
                float f[8];
                uint4 k1 = *(const uint4*)kp;       b8tof(k1, f);
#pragma unroll
                for (int u = 0; u < 8; ++u) KPs[lc + u][lr] = f[u];
                uint4 k2 = *(const uint4*)(kp + 8); b8tof(k2, f);
#pragma unroll
                for (int u = 0; u < 8; ++u) KPs[lc + 8 + u][lr] = f[u];
                uint4 w1 = *(const uint4*)vp;       b8tof(w1, f);
#pragma unroll
                for (int u = 0; u < 8; ++u) Vs[lr][lc + u] = f[u];
                uint4 w2 = *(const uint4*)(vp + 8); b8tof(w2, f);
#pragma unroll
                for (int u = 0; u < 8; ++u) Vs[lr][lc + 8 + u] = f[u];
            }
        }
        __syncthreads();

        // ---- S = (Q @ K^T) * 0.125 ----
        float s[4][4];
#pragma unroll
        for (int i = 0; i < 4; ++i)
#pragma unroll
            for (int j = 0; j < 4; ++j) s[i][j] = 0.0f;

#pragma unroll
        for (int d4 = 0; d4 < 16; ++d4) {
            float4 qv[4], kv[4];
#pragma unroll
            for (int i = 0; i < 4; ++i) qv[i] = *(const float4*)&Qs[ty * 4 + i][d4 * 4];
#pragma unroll
            for (int dd = 0; dd < 4; ++dd) kv[dd] = *(const float4*)&KPs[d4 * 4 + dd][tx * 4];
#pragma unroll
            for (int i = 0; i < 4; ++i) {
                const float q0 = qv[i].x, q1 = qv[i].y, q2 = qv[i].z, q3 = qv[i].w;
#pragma unroll
                for (int j = 0; j < 4; ++j) {
                    const float k0 = (&kv[0].x)[j], k1 = (&kv[1].x)[j],
                                k2 = (&kv[2].x)[j], k3 = (&kv[3].x)[j];
                    s[i][j] += q0 * k0 + q1 * k1 + q2 * k2 + q3 * k3;
                }
            }
        }

        const int jg0 = kt * 64 + tx * 4;
#pragma unroll
        for (int i = 0; i < 4; ++i)
#pragma unroll
            for (int j = 0; j < 4; ++j) s[i][j] *= 0.125f;

        if (CAUSAL && kt == qt) {
#pragma unroll
            for (int i = 0; i < 4; ++i)
#pragma unroll
                for (int j = 0; j < 4; ++j)
                    if (jg0 + j > ig0 + i) s[i][j] = -INFINITY;
        }
        if (!CAUSAL && kt == nkt - 1) {
#pragma unroll
            for (int i = 0; i < 4; ++i)
#pragma unroll
                for (int j = 0; j < 4; ++j)
                    if (jg0 + j >= Sk) s[i][j] = -INFINITY;
        }

        __syncthreads();  // done reading Kst before P overwrite

        // ---- online softmax ----
        float mt[4], sf[4], rs[4];
#pragma unroll
        for (int i = 0; i < 4; ++i)
            mt[i] = fmaxf(fmaxf(s[i][0], s[i][1]), fmaxf(s[i][2], s[i][3]));
#pragma unroll
        for (int off = 1; off < 16; off <<= 1)
#pragma unroll
            for (int i = 0; i < 4; ++i) mt[i] = fmaxf(mt[i], __shfl_xor(mt[i], off));
#pragma unroll
        for (int i = 0; i < 4; ++i) {
            const float mn = fmaxf(m_run[i], mt[i]);
            sf[i] = expf(m_run[i] - mn);
            m_run[i] = mn;
            rs[i] = 0.0f;
#pragma unroll
            for (int j = 0; j < 4; ++j) {
                const float p = expf(s[i][j] - mn);
                s[i][j] = p;
                rs[i] += p;
            }
        }
#pragma unroll
        for (int off = 1; off < 16; off <<= 1)
#pragma unroll
            for (int i = 0; i < 4; ++i) rs[i] += __shfl_xor(rs[i], off);
#pragma unroll
        for (int i = 0; i < 4; ++i) {
            l_run[i] = l_run[i] * sf[i] + rs[i];
            *(float4*)&KPs[ty * 4 + i][tx * 4] = make_float4(s[i][0], s[i][1], s[i][2], s[i][3]);
#pragma unroll
            for (int c = 0; c < 4; ++c) oacc[i][c] *= sf[i];
        }
        __syncthreads();

        // ---- O += P @ V ----
#pragma unroll
        for (int j4 = 0; j4 < 16; ++j4) {
            float4 pv[4], vr[4];
#pragma unroll
            for (int i = 0; i < 4; ++i) pv[i] = *(const float4*)&KPs[ty * 4 + i][j4 * 4];
#pragma unroll
            for (int jj = 0; jj < 4; ++jj) vr[jj] = *(const float4*)&Vs[j4 * 4 + jj][tx * 4];
#pragma unroll
            for (int i = 0; i < 4; ++i) {
#pragma unroll
                for (int c = 0; c < 4; ++c) {
                    oacc[i][c] += pv[i].x * (&vr[0].x)[c] + pv[i].y * (&vr[1].x)[c]
                                + pv[i].z * (&vr[2].x)[c] + pv[i].w * (&vr[3].x)[c];
                }
            }
        }
    }

    // ---- epilogue: normalize, cast bf16 ----
#pragma unroll
    for (int i = 0; i < 4; ++i) {
        const float inv = 1.0f / l_run[i];
        const size_t r = (size_t)(b * Sq + qt * 64 + ty * 4 + i);
        ushort4 ov;
        ov.x = f2b(oacc[i][0] * inv); ov.y = f2b(oacc[i][1] * inv);
        ov.z = f2b(oacc[i][2] * inv); ov.w = f2b(oacc[i][3] * inv);
        *(ushort4*)&O[r * D_MODEL + h * DHEAD + tx * 4] = ov;
    }
}

// ---------------------------------------------------------------------------
// Orchestration
// ---------------------------------------------------------------------------
extern "C" void kernel_launch(void* const* d_in, const int* in_sizes, int n_in,
                              void* d_out, int out_size, void* d_ws, size_t ws_size,
                              hipStream_t stream)
{
    const int B = 4, S = 1024, T = 1500, DFF = 4096;
    const int MS = B * S;    // 4096
    const int MT = B * T;    // 6000
    const int MTP = 6016;    // padded to x128

    const float* x          = (const float*)d_in[0];
    const float* xa         = (const float*)d_in[1];
    const float* attn_ln_g  = (const float*)d_in[3];
    const float* attn_ln_b  = (const float*)d_in[4];
    const float* sa_wq      = (const float*)d_in[5];
    const float* sa_bq      = (const float*)d_in[6];
    const float* sa_wk      = (const float*)d_in[7];
    const float* sa_wv      = (const float*)d_in[8];
    const float* sa_bv      = (const float*)d_in[9];
    const float* sa_wo      = (const float*)d_in[10];
    const float* sa_bo      = (const float*)d_in[11];
    const float* cross_ln_g = (const float*)d_in[12];
    const float* cross_ln_b = (const float*)d_in[13];
    const float* ca_wq      = (const float*)d_in[14];
    const float* ca_bq      = (const float*)d_in[15];
    const float* ca_wk      = (const float*)d_in[16];
    const float* ca_wv      = (const float*)d_in[17];
    const float* ca_bv      = (const float*)d_in[18];
    const float* ca_wo      = (const float*)d_in[19];
    const float* ca_bo      = (const float*)d_in[20];
    const float* mlp_ln_g   = (const float*)d_in[21];
    const float* mlp_ln_b   = (const float*)d_in[22];
    const float* mlp_w1     = (const float*)d_in[23];
    const float* mlp_b1     = (const float*)d_in[24];
    const float* mlp_w2     = (const float*)d_in[25];
    const float* mlp_b2     = (const float*)d_in[26];

    char* base = (char*)d_ws;
    size_t off = 0;
    auto alloc = [&](size_t bytes) -> void* {
        void* p = base + off; off += (bytes + 255) & ~(size_t)255; return p;
    };

    typedef unsigned short u16;
    const size_t DD2 = (size_t)D_MODEL * D_MODEL * 2;
    u16* sa_wqT = (u16*)alloc(DD2);
    u16* sa_wkT = (u16*)alloc(DD2);
    u16* sa_wvT = (u16*)alloc(DD2);
    u16* sa_woT = (u16*)alloc(DD2);
    u16* ca_wqT = (u16*)alloc(DD2);
    u16* ca_wkT = (u16*)alloc(DD2);
    u16* ca_wvT = (u16*)alloc(DD2);
    u16* ca_woT = (u16*)alloc(DD2);
    u16* w1T    = (u16*)alloc((size_t)D_MODEL * DFF * 2);   // [DFF][D]
    u16* w2T    = (u16*)alloc((size_t)D_MODEL * DFF * 2);   // [D][DFF]

    u16*   lnb = (u16*)alloc((size_t)MS * D_MODEL * 2);
    float* r1  = (float*)alloc((size_t)MS * D_MODEL * 4);
    u16*   ab  = (u16*)alloc((size_t)MS * D_MODEL * 2);

    char* qkv0 = (char*)alloc((size_t)MS * D_MODEL * 2      // qb
                            + (size_t)MTP * D_MODEL * 2     // kb
                            + (size_t)MTP * D_MODEL * 2     // vb
                            + (size_t)MTP * D_MODEL * 2);   // xab
    u16* qb  = (u16*)qkv0;
    u16* kb  = qb + (size_t)MS * D_MODEL;
    u16* vb  = kb + (size_t)MTP * D_MODEL;
    u16* xab = vb + (size_t)MTP * D_MODEL;
    u16* hb  = (u16*)qkv0;   // [MS][DFF] aliases q/k/v (+xab) region in MLP phase

    // ---- prep: weight transpose+convert, xa convert ----
    dim3 tb(32, 8);
    wtrans_kernel<<<dim3(D_MODEL/32, D_MODEL/32), tb, 0, stream>>>(sa_wq, sa_wqT, D_MODEL, D_MODEL);
    wtrans_kernel<<<dim3(D_MODEL/32, D_MODEL/32), tb, 0, stream>>>(sa_wk, sa_wkT, D_MODEL, D_MODEL);
    wtrans_kernel<<<dim3(D_MODEL/32, D_MODEL/32), tb, 0, stream>>>(sa_wv, sa_wvT, D_MODEL, D_MODEL);
    wtrans_kernel<<<dim3(D_MODEL/32, D_MODEL/32), tb, 0, stream>>>(sa_wo, sa_woT, D_MODEL, D_MODEL);
    wtrans_kernel<<<dim3(D_MODEL/32, D_MODEL/32), tb, 0, stream>>>(ca_wq, ca_wqT, D_MODEL, D_MODEL);
    wtrans_kernel<<<dim3(D_MODEL/32, D_MODEL/32), tb, 0, stream>>>(ca_wk, ca_wkT, D_MODEL, D_MODEL);
    wtrans_kernel<<<dim3(D_MODEL/32, D_MODEL/32), tb, 0, stream>>>(ca_wv, ca_wvT, D_MODEL, D_MODEL);
    wtrans_kernel<<<dim3(D_MODEL/32, D_MODEL/32), tb, 0, stream>>>(ca_wo, ca_woT, D_MODEL, D_MODEL);
    wtrans_kernel<<<dim3(DFF/32, D_MODEL/32), tb, 0, stream>>>(mlp_w1, w1T, D_MODEL, DFF);
    wtrans_kernel<<<dim3(D_MODEL/32, DFF/32), tb, 0, stream>>>(mlp_w2, w2T, DFF, D_MODEL);
    f2b_kernel<<<1024, 256, 0, stream>>>(xa, xab, MT * D_MODEL / 4);

    auto gemm = [&](const u16* A, const u16* Wt, const float* bias, const float* resid,
                    void* C, int M, int N, int K, bool gelu, bool obf16) {
        dim3 grid(N / 128, (M + 127) / 128);
        if (gelu)            mfma_gemm<true,  true ><<<grid, 256, 0, stream>>>(A, Wt, bias, resid, C, M, N, K);
        else if (obf16)      mfma_gemm<false, true ><<<grid, 256, 0, stream>>>(A, Wt, bias, resid, C, M, N, K);
        else                 mfma_gemm<false, false><<<grid, 256, 0, stream>>>(A, Wt, bias, resid, C, M, N, K);
    };

    // ---- self-attention block ----
    ln_kernel<<<MS, 256, 0, stream>>>(x, attn_ln_g, attn_ln_b, lnb);
    gemm(lnb, sa_wqT, sa_bq, nullptr, qb, MS, D_MODEL, D_MODEL, false, true);
    gemm(lnb, sa_wkT, nullptr, nullptr, kb, MS, D_MODEL, D_MODEL, false, true);
    gemm(lnb, sa_wvT, sa_bv, nullptr, vb, MS, D_MODEL, D_MODEL, false, true);
    fattn_kernel<true><<<dim3(S / 64, NH, B), 256, 0, stream>>>(qb, kb, vb, ab, S, S);
    gemm(ab, sa_woT, sa_bo, x, r1, MS, D_MODEL, D_MODEL, false, false);

    // ---- cross-attention block ----
    ln_kernel<<<MS, 256, 0, stream>>>(r1, cross_ln_g, cross_ln_b, lnb);
    gemm(lnb, ca_wqT, ca_bq, nullptr, qb, MS, D_MODEL, D_MODEL, false, true);
    gemm(xab, ca_wkT, nullptr, nullptr, kb, MT, D_MODEL, D_MODEL, false, true);
    gemm(xab, ca_wvT, ca_bv, nullptr, vb, MT, D_MODEL, D_MODEL, false, true);
    fattn_kernel<false><<<dim3(S / 64, NH, B), 256, 0, stream>>>(qb, kb, vb, ab, S, T);
    gemm(ab, ca_woT, ca_bo, r1, r1, MS, D_MODEL, D_MODEL, false, false);

    // ---- MLP block ----
    ln_kernel<<<MS, 256, 0, stream>>>(r1, mlp_ln_g, mlp_ln_b, lnb);
    gemm(lnb, w1T, mlp_b1, nullptr, hb, MS, DFF, D_MODEL, true, true);
    gemm(hb, w2T, mlp_b2, r1, d_out, MS, D_MODEL, DFF, false, false);
}

// Round 12
// 880.332 us; speedup vs baseline: 11.9843x; 1.9934x over previous
//
#include <hip/hip_runtime.h>
#include <math.h>

#define D_MODEL 1024
#define NH      16
#define DHEAD   64
#define LDK     40   // GEMM LDS K-stride (bf16) -> 80B rows, ~2-way banks
#define LDA     72   // attn LDS row stride (bf16) -> 144B rows, 16B-aligned, ~2-way banks

typedef __attribute__((ext_vector_type(8))) short bf16x8;
typedef __attribute__((ext_vector_type(4))) float f32x4;

__device__ __forceinline__ unsigned short f2b(float f) {
    union { float f; unsigned u; } v; v.f = f;
    unsigned r = v.u + 0x7FFFu + ((v.u >> 16) & 1u);   // RNE
    return (unsigned short)(r >> 16);
}
__device__ __forceinline__ float gelu_exact(float x) {
    return 0.5f * x * (1.0f + erff(x * 0.70710678118654752440f));
}

// ---------------------------------------------------------------------------
// LayerNorm: fp32 in, bf16 out (feeds MFMA GEMMs)
// ---------------------------------------------------------------------------
__global__ __launch_bounds__(256) void ln_kernel(
    const float* __restrict__ X, const float* __restrict__ g,
    const float* __restrict__ bta, unsigned short* __restrict__ Y)
{
    __shared__ float red[8];
    const int row = blockIdx.x;
    const int tid = threadIdx.x;
    const float* x = X + (size_t)row * D_MODEL;

    float4 v = *(const float4*)&x[tid * 4];
    float s  = v.x + v.y + v.z + v.w;
    float sq = v.x * v.x + v.y * v.y + v.z * v.z + v.w * v.w;
#pragma unroll
    for (int o = 32; o > 0; o >>= 1) {
        s  += __shfl_down(s, o);
        sq += __shfl_down(sq, o);
    }
    if ((tid & 63) == 0) { red[tid >> 6] = s; red[4 + (tid >> 6)] = sq; }
    __syncthreads();
    const float ts = red[0] + red[1] + red[2] + red[3];
    const float tq = red[4] + red[5] + red[6] + red[7];
    const float mu   = ts * (1.0f / D_MODEL);
    const float var  = tq * (1.0f / D_MODEL) - mu * mu;
    const float rstd = 1.0f / sqrtf(var + 1e-5f);

    const float4 gv = *(const float4*)&g[tid * 4];
    const float4 bv = *(const float4*)&bta[tid * 4];
    ushort4 y;
    y.x = f2b((v.x - mu) * rstd * gv.x + bv.x);
    y.y = f2b((v.y - mu) * rstd * gv.y + bv.y);
    y.z = f2b((v.z - mu) * rstd * gv.z + bv.z);
    y.w = f2b((v.w - mu) * rstd * gv.w + bv.w);
    *(ushort4*)&Y[(size_t)row * D_MODEL + tid * 4] = y;
}

// ---------------------------------------------------------------------------
// fp32 -> bf16 elementwise (for xa)
// ---------------------------------------------------------------------------
__global__ __launch_bounds__(256) void f2b_kernel(
    const float* __restrict__ in, unsigned short* __restrict__ out, int n4)
{
    int i = blockIdx.x * blockDim.x + threadIdx.x;
    for (; i < n4; i += gridDim.x * blockDim.x) {
        float4 v = ((const float4*)in)[i];
        ushort4 o; o.x = f2b(v.x); o.y = f2b(v.y); o.z = f2b(v.z); o.w = f2b(v.w);
        ((ushort4*)out)[i] = o;
    }
}

// ---------------------------------------------------------------------------
// Weight transpose+convert: W[K][N] fp32 -> Wt[N][K] bf16
// ---------------------------------------------------------------------------
__global__ __launch_bounds__(256) void wtrans_kernel(
    const float* __restrict__ W, unsigned short* __restrict__ Wt, int K, int N)
{
    __shared__ float t[32][33];
    const int n0 = blockIdx.x * 32, k0 = blockIdx.y * 32;
    const int tx = threadIdx.x, ty = threadIdx.y;  // (32, 8)
#pragma unroll
    for (int i = 0; i < 4; ++i)
        t[ty + i * 8][tx] = W[(size_t)(k0 + ty + i * 8) * N + n0 + tx];
    __syncthreads();
#pragma unroll
    for (int i = 0; i < 4; ++i)
        Wt[(size_t)(n0 + ty + i * 8) * K + k0 + tx] = f2b(t[tx][ty + i * 8]);
}

// ---------------------------------------------------------------------------
// BF16 MFMA GEMM: C[M,N] = A[M,K] @ Wt[N,K]^T (+bias)(+resid)(+GELU)
// 128x128 tile, BK=32, 256 thr = 4 waves (2x2 of 64x64), 16x16x32 MFMA.
// ---------------------------------------------------------------------------
template <bool GELU, bool OBF16>
__global__ __launch_bounds__(256) void mfma_gemm(
    const unsigned short* __restrict__ A, const unsigned short* __restrict__ Wt,
    const float* __restrict__ bias, const float* __restrict__ resid,
    void* __restrict__ C, int M, int N, int K)
{
    __shared__ unsigned short As[128 * LDK];
    __shared__ unsigned short Bs[128 * LDK];

    const int tid  = threadIdx.x;
    const int row0 = blockIdx.y * 128;
    const int col0 = blockIdx.x * 128;
    const int l = tid & 63, w = tid >> 6;
    const int wr = (w >> 1) * 64, wc = (w & 1) * 64;
    const int sr = tid >> 1;            // staging row 0..127
    const int sc = (tid & 1) * 16;      // staging col 0/16

    f32x4 acc[4][4] = {};

    const unsigned short* Ap = A  + (size_t)(row0 + sr) * K + sc;
    const unsigned short* Bp = Wt + (size_t)(col0 + sr) * K + sc;

    uint4 a0 = *(const uint4*)(Ap);     uint4 a1 = *(const uint4*)(Ap + 8);
    uint4 b0 = *(const uint4*)(Bp);     uint4 b1 = *(const uint4*)(Bp + 8);

    const int fr = l & 15, fk = (l >> 4) * 8;

    for (int kt = 0; kt < K; kt += 32) {
        __syncthreads();
        *(uint4*)&As[sr * LDK + sc]     = a0;
        *(uint4*)&As[sr * LDK + sc + 8] = a1;
        *(uint4*)&Bs[sr * LDK + sc]     = b0;
        *(uint4*)&Bs[sr * LDK + sc + 8] = b1;
        __syncthreads();
        if (kt + 32 < K) {   // prefetch next K-tile
            a0 = *(const uint4*)(Ap + kt + 32); a1 = *(const uint4*)(Ap + kt + 40);
            b0 = *(const uint4*)(Bp + kt + 32); b1 = *(const uint4*)(Bp + kt + 40);
        }
        bf16x8 af[4], bf[4];
#pragma unroll
        for (int m = 0; m < 4; ++m)
            af[m] = *(const bf16x8*)&As[(wr + m * 16 + fr) * LDK + fk];
#pragma unroll
        for (int n = 0; n < 4; ++n)
            bf[n] = *(const bf16x8*)&Bs[(wc + n * 16 + fr) * LDK + fk];
#pragma unroll
        for (int m = 0; m < 4; ++m)
#pragma unroll
            for (int n = 0; n < 4; ++n)
                acc[m][n] = __builtin_amdgcn_mfma_f32_16x16x32_bf16(
                    af[m], bf[n], acc[m][n], 0, 0, 0);
    }

    // epilogue: C/D layout col=l&15, row=(l>>4)*4+i  [verified m89 + round-9 pass]
    const int fq = l >> 4;
#pragma unroll
    for (int m = 0; m < 4; ++m) {
#pragma unroll
        for (int i = 0; i < 4; ++i) {
            const int r = row0 + wr + m * 16 + fq * 4 + i;
            if (r < M) {
#pragma unroll
                for (int n = 0; n < 4; ++n) {
                    const int c = col0 + wc + n * 16 + fr;
                    float v = acc[m][n][i];
                    if (bias)  v += bias[c];
                    if (resid) v += resid[(size_t)r * N + c];
                    if (GELU)  v = gelu_exact(v);
                    if (OBF16) ((unsigned short*)C)[(size_t)r * N + c] = f2b(v);
                    else       ((float*)C)[(size_t)r * N + c] = v;
                }
            }
        }
    }
}

// ---------------------------------------------------------------------------
// MFMA flash attention: bf16 Q/K/V in, bf16 O out, fp32 softmax/accum.
// One block per (q-tile 64, h, b), 256 thr = 4 waves; wave w owns q-rows
// w*16..w*16+15 x ALL 64 k-cols (softmax reduce stays within the wave's
// 16-lane groups). QK^T: A=Q[seq][d], B=K[seq][d] (GEMM A.Wt^T pattern).
// PV: A=P[q][k] (bf16, staged via LDS), B=V^T[d][k] (transposed at staging).
// Causal: skip k-tiles > qt, mask diagonal; cross tail masked + zero-filled.
// ---------------------------------------------------------------------------
template <bool CAUSAL>
__global__ __launch_bounds__(256) void mfattn_kernel(
    const unsigned short* __restrict__ Q, const unsigned short* __restrict__ K,
    const unsigned short* __restrict__ V, unsigned short* __restrict__ O,
    int Sq, int Sk)
{
    __shared__ unsigned short Qs[64 * LDA];
    __shared__ unsigned short Ks[64 * LDA];
    __shared__ unsigned short Vt[64 * LDA];   // V transposed: [d][k]
    __shared__ unsigned short Ps[64 * LDA];   // P bf16: [q][k]

    const int qt  = blockIdx.x;
    const int h   = blockIdx.y;
    const int b   = blockIdx.z;
    const int tid = threadIdx.x;
    const int l   = tid & 63, w = tid >> 6;
    const int fr  = l & 15;            // fragment row/col index
    const int fk  = (l >> 4) * 8;      // fragment k offset
    const int fq  = l >> 4;            // C/D row group

    // staging coords: 64 rows x 64 cols, each thread 16 consecutive elems
    const int srow = tid >> 2;         // 0..63
    const int sc8  = (tid & 3) * 16;   // 0,16,32,48

    // ---- stage Q tile ----
    {
        const unsigned short* qg =
            Q + ((size_t)(b * Sq + qt * 64 + srow)) * D_MODEL + h * DHEAD;
        *(uint4*)&Qs[srow * LDA + sc8]     = *(const uint4*)&qg[sc8];
        *(uint4*)&Qs[srow * LDA + sc8 + 8] = *(const uint4*)&qg[sc8 + 8];
    }
    __syncthreads();

    // Q fragments (rows w*16.., K=64 in 2 halves) — tile-invariant, hoisted
    bf16x8 aq0 = *(const bf16x8*)&Qs[(w * 16 + fr) * LDA + fk];
    bf16x8 aq1 = *(const bf16x8*)&Qs[(w * 16 + fr) * LDA + 32 + fk];

    f32x4 o_acc[4] = {};               // [n=d-block]; rows fq*4+i
    float m_run[4], l_run[4];
#pragma unroll
    for (int i = 0; i < 4; ++i) { m_run[i] = -INFINITY; l_run[i] = 0.0f; }

    const int rg0 = qt * 64 + w * 16 + fq * 4;   // + i -> global q row
    const int nkt = CAUSAL ? (qt + 1) : ((Sk + 63) >> 6);

    for (int kt = 0; kt < nkt; ++kt) {
        __syncthreads();   // prev PV done before overwriting Ks/Vt (and Ps safe)
        {
            const int kr = kt * 64 + srow;
            if (!CAUSAL && kr >= Sk) {
                const uint4 z = make_uint4(0, 0, 0, 0);
                *(uint4*)&Ks[srow * LDA + sc8]     = z;
                *(uint4*)&Ks[srow * LDA + sc8 + 8] = z;
#pragma unroll
                for (int u = 0; u < 16; ++u) Vt[(sc8 + u) * LDA + srow] = 0;
            } else {
                const unsigned short* kg =
                    K + ((size_t)(b * Sk + kr)) * D_MODEL + h * DHEAD;
                const unsigned short* vg =
                    V + ((size_t)(b * Sk + kr)) * D_MODEL + h * DHEAD;
                *(uint4*)&Ks[srow * LDA + sc8]     = *(const uint4*)&kg[sc8];
                *(uint4*)&Ks[srow * LDA + sc8 + 8] = *(const uint4*)&kg[sc8 + 8];
                union { uint4 v; unsigned short s[8]; } v0, v1;
                v0.v = *(const uint4*)&vg[sc8];
                v1.v = *(const uint4*)&vg[sc8 + 8];
#pragma unroll
                for (int u = 0; u < 8; ++u) {
                    Vt[(sc8 + u) * LDA + srow]     = v0.s[u];
                    Vt[(sc8 + 8 + u) * LDA + srow] = v1.s[u];
                }
            }
        }
        __syncthreads();

        // ---- S = Q @ K^T (per wave: 16 rows x 64 cols) ----
        f32x4 s_acc[4] = {};
#pragma unroll
        for (int n = 0; n < 4; ++n) {
            bf16x8 bk0 = *(const bf16x8*)&Ks[(n * 16 + fr) * LDA + fk];
            bf16x8 bk1 = *(const bf16x8*)&Ks[(n * 16 + fr) * LDA + 32 + fk];
            s_acc[n] = __builtin_amdgcn_mfma_f32_16x16x32_bf16(aq0, bk0, s_acc[n], 0, 0, 0);
            s_acc[n] = __builtin_amdgcn_mfma_f32_16x16x32_bf16(aq1, bk1, s_acc[n], 0, 0, 0);
        }

        // ---- scale + mask ----
        float s[4][4];   // [i=row][n=col-block]; col = kt*64 + n*16 + fr
        const int cg0 = kt * 64 + fr;
#pragma unroll
        for (int i = 0; i < 4; ++i)
#pragma unroll
            for (int n = 0; n < 4; ++n) s[i][n] = s_acc[n][i] * 0.125f;
        if (CAUSAL && kt == qt) {
#pragma unroll
            for (int i = 0; i < 4; ++i)
#pragma unroll
                for (int n = 0; n < 4; ++n)
                    if (cg0 + n * 16 > rg0 + i) s[i][n] = -INFINITY;
        }
        if (!CAUSAL && kt == nkt - 1) {
#pragma unroll
            for (int i = 0; i < 4; ++i)
#pragma unroll
                for (int n = 0; n < 4; ++n)
                    if (cg0 + n * 16 >= Sk) s[i][n] = -INFINITY;
        }

        // ---- online softmax (row reduce: 4 local + shfl_xor over 16 lanes) ----
        float mt[4], sf[4], rs[4];
#pragma unroll
        for (int i = 0; i < 4; ++i)
            mt[i] = fmaxf(fmaxf(s[i][0], s[i][1]), fmaxf(s[i][2], s[i][3]));
#pragma unroll
        for (int off = 1; off < 16; off <<= 1)
#pragma unroll
            for (int i = 0; i < 4; ++i) mt[i] = fmaxf(mt[i], __shfl_xor(mt[i], off));
#pragma unroll
        for (int i = 0; i < 4; ++i) {
            const float mn = fmaxf(m_run[i], mt[i]);
            sf[i] = expf(m_run[i] - mn);
            m_run[i] = mn;
            rs[i] = 0.0f;
#pragma unroll
            for (int n = 0; n < 4; ++n) {
                const float p = expf(s[i][n] - mn);
                s[i][n] = p;
                rs[i] += p;
            }
        }
#pragma unroll
        for (int off = 1; off < 16; off <<= 1)
#pragma unroll
            for (int i = 0; i < 4; ++i) rs[i] += __shfl_xor(rs[i], off);

        // ---- write P (bf16), rescale O ----
#pragma unroll
        for (int i = 0; i < 4; ++i) {
            l_run[i] = l_run[i] * sf[i] + rs[i];
            const int pr = (w * 16 + fq * 4 + i) * LDA;
#pragma unroll
            for (int n = 0; n < 4; ++n)
                Ps[pr + n * 16 + fr] = f2b(s[i][n]);
        }
#pragma unroll
        for (int n = 0; n < 4; ++n)
#pragma unroll
            for (int i = 0; i < 4; ++i) o_acc[n][i] *= sf[i];
        __syncthreads();   // P visible

        // ---- O += P @ V  (A=P[q][k], B=V^T[d][k]) ----
        bf16x8 ap0 = *(const bf16x8*)&Ps[(w * 16 + fr) * LDA + fk];
        bf16x8 ap1 = *(const bf16x8*)&Ps[(w * 16 + fr) * LDA + 32 + fk];
#pragma unroll
        for (int n = 0; n < 4; ++n) {
            bf16x8 bv0 = *(const bf16x8*)&Vt[(n * 16 + fr) * LDA + fk];
            bf16x8 bv1 = *(const bf16x8*)&Vt[(n * 16 + fr) * LDA + 32 + fk];
            o_acc[n] = __builtin_amdgcn_mfma_f32_16x16x32_bf16(ap0, bv0, o_acc[n], 0, 0, 0);
            o_acc[n] = __builtin_amdgcn_mfma_f32_16x16x32_bf16(ap1, bv1, o_acc[n], 0, 0, 0);
        }
    }

    // ---- epilogue ----
#pragma unroll
    for (int i = 0; i < 4; ++i) {
        const float inv = 1.0f / l_run[i];
        const size_t r = (size_t)(b * Sq + qt * 64 + w * 16 + fq * 4 + i);
#pragma unroll
        for (int n = 0; n < 4; ++n)
            O[r * D_MODEL + h * DHEAD + n * 16 + fr] = f2b(o_acc[n][i] * inv);
    }
}

// ---------------------------------------------------------------------------
// Orchestration
// ---------------------------------------------------------------------------
extern "C" void kernel_launch(void* const* d_in, const int* in_sizes, int n_in,
                              void* d_out, int out_size, void* d_ws, size_t ws_size,
                              hipStream_t stream)
{
    const int B = 4, S = 1024, T = 1500, DFF = 4096;
    const int MS = B * S;    // 4096
    const int MT = B * T;    // 6000
    const int MTP = 6016;    // padded to x128

    const float* x          = (const float*)d_in[0];
    const float* xa         = (const float*)d_in[1];
    const float* attn_ln_g  = (const float*)d_in[3];
    const float* attn_ln_b  = (const float*)d_in[4];
    const float* sa_wq      = (const float*)d_in[5];
    const float* sa_bq      = (const float*)d_in[6];
    const float* sa_wk      = (const float*)d_in[7];
    const float* sa_wv      = (const float*)d_in[8];
    const float* sa_bv      = (const float*)d_in[9];
    const float* sa_wo      = (const float*)d_in[10];
    const float* sa_bo      = (const float*)d_in[11];
    const float* cross_ln_g = (const float*)d_in[12];
    const float* cross_ln_b = (const float*)d_in[13];
    const float* ca_wq      = (const float*)d_in[14];
    const float* ca_bq      = (const float*)d_in[15];
    const float* ca_wk      = (const float*)d_in[16];
    const float* ca_wv      = (const float*)d_in[17];
    const float* ca_bv      = (const float*)d_in[18];
    const float* ca_wo      = (const float*)d_in[19];
    const float* ca_bo      = (const float*)d_in[20];
    const float* mlp_ln_g   = (const float*)d_in[21];
    const float* mlp_ln_b   = (const float*)d_in[22];
    const float* mlp_w1     = (const float*)d_in[23];
    const float* mlp_b1     = (const float*)d_in[24];
    const float* mlp_w2     = (const float*)d_in[25];
    const float* mlp_b2     = (const float*)d_in[26];

    char* base = (char*)d_ws;
    size_t off = 0;
    auto alloc = [&](size_t bytes) -> void* {
        void* p = base + off; off += (bytes + 255) & ~(size_t)255; return p;
    };

    typedef unsigned short u16;
    const size_t DD2 = (size_t)D_MODEL * D_MODEL * 2;
    u16* sa_wqT = (u16*)alloc(DD2);
    u16* sa_wkT = (u16*)alloc(DD2);
    u16* sa_wvT = (u16*)alloc(DD2);
    u16* sa_woT = (u16*)alloc(DD2);
    u16* ca_wqT = (u16*)alloc(DD2);
    u16* ca_wkT = (u16*)alloc(DD2);
    u16* ca_wvT = (u16*)alloc(DD2);
    u16* ca_woT = (u16*)alloc(DD2);
    u16* w1T    = (u16*)alloc((size_t)D_MODEL * DFF * 2);   // [DFF][D]
    u16* w2T    = (u16*)alloc((size_t)D_MODEL * DFF * 2);   // [D][DFF]

    u16*   lnb = (u16*)alloc((size_t)MS * D_MODEL * 2);
    float* r1  = (float*)alloc((size_t)MS * D_MODEL * 4);
    u16*   ab  = (u16*)alloc((size_t)MS * D_MODEL * 2);

    char* qkv0 = (char*)alloc((size_t)MS * D_MODEL * 2      // qb
                            + (size_t)MTP * D_MODEL * 2     // kb
                            + (size_t)MTP * D_MODEL * 2     // vb
                            + (size_t)MTP * D_MODEL * 2);   // xab
    u16* qb  = (u16*)qkv0;
    u16* kb  = qb + (size_t)MS * D_MODEL;
    u16* vb  = kb + (size_t)MTP * D_MODEL;
    u16* xab = vb + (size_t)MTP * D_MODEL;
    u16* hb  = (u16*)qkv0;   // [MS][DFF] aliases q/k/v (+xab) region in MLP phase

    // ---- prep: weight transpose+convert, xa convert ----
    dim3 tb(32, 8);
    wtrans_kernel<<<dim3(D_MODEL/32, D_MODEL/32), tb, 0, stream>>>(sa_wq, sa_wqT, D_MODEL, D_MODEL);
    wtrans_kernel<<<dim3(D_MODEL/32, D_MODEL/32), tb, 0, stream>>>(sa_wk, sa_wkT, D_MODEL, D_MODEL);
    wtrans_kernel<<<dim3(D_MODEL/32, D_MODEL/32), tb, 0, stream>>>(sa_wv, sa_wvT, D_MODEL, D_MODEL);
    wtrans_kernel<<<dim3(D_MODEL/32, D_MODEL/32), tb, 0, stream>>>(sa_wo, sa_woT, D_MODEL, D_MODEL);
    wtrans_kernel<<<dim3(D_MODEL/32, D_MODEL/32), tb, 0, stream>>>(ca_wq, ca_wqT, D_MODEL, D_MODEL);
    wtrans_kernel<<<dim3(D_MODEL/32, D_MODEL/32), tb, 0, stream>>>(ca_wk, ca_wkT, D_MODEL, D_MODEL);
    wtrans_kernel<<<dim3(D_MODEL/32, D_MODEL/32), tb, 0, stream>>>(ca_wv, ca_wvT, D_MODEL, D_MODEL);
    wtrans_kernel<<<dim3(D_MODEL/32, D_MODEL/32), tb, 0, stream>>>(ca_wo, ca_woT, D_MODEL, D_MODEL);
    wtrans_kernel<<<dim3(DFF/32, D_MODEL/32), tb, 0, stream>>>(mlp_w1, w1T, D_MODEL, DFF);
    wtrans_kernel<<<dim3(D_MODEL/32, DFF/32), tb, 0, stream>>>(mlp_w2, w2T, DFF, D_MODEL);
    f2b_kernel<<<1024, 256, 0, stream>>>(xa, xab, MT * D_MODEL / 4);

    auto gemm = [&](const u16* A, const u16* Wt, const float* bias, const float* resid,
                    void* C, int M, int N, int K, bool gelu, bool obf16) {
        dim3 grid(N / 128, (M + 127) / 128);
        if (gelu)            mfma_gemm<true,  true ><<<grid, 256, 0, stream>>>(A, Wt, bias, resid, C, M, N, K);
        else if (obf16)      mfma_gemm<false, true ><<<grid, 256, 0, stream>>>(A, Wt, bias, resid, C, M, N, K);
        else                 mfma_gemm<false, false><<<grid, 256, 0, stream>>>(A, Wt, bias, resid, C, M, N, K);
    };

    // ---- self-attention block ----
    ln_kernel<<<MS, 256, 0, stream>>>(x, attn_ln_g, attn_ln_b, lnb);
    gemm(lnb, sa_wqT, sa_bq, nullptr, qb, MS, D_MODEL, D_MODEL, false, true);
    gemm(lnb, sa_wkT, nullptr, nullptr, kb, MS, D_MODEL, D_MODEL, false, true);
    gemm(lnb, sa_wvT, sa_bv, nullptr, vb, MS, D_MODEL, D_MODEL, false, true);
    mfattn_kernel<true><<<dim3(S / 64, NH, B), 256, 0, stream>>>(qb, kb, vb, ab, S, S);
    gemm(ab, sa_woT, sa_bo, x, r1, MS, D_MODEL, D_MODEL, false, false);

    // ---- cross-attention block ----
    ln_kernel<<<MS, 256, 0, stream>>>(r1, cross_ln_g, cross_ln_b, lnb);
    gemm(lnb, ca_wqT, ca_bq, nullptr, qb, MS, D_MODEL, D_MODEL, false, true);
    gemm(xab, ca_wkT, nullptr, nullptr, kb, MT, D_MODEL, D_MODEL, false, true);
    gemm(xab, ca_wvT, ca_bv, nullptr, vb, MT, D_MODEL, D_MODEL, false, true);
    mfattn_kernel<false><<<dim3(S / 64, NH, B), 256, 0, stream>>>(qb, kb, vb, ab, S, T);
    gemm(ab, ca_woT, ca_bo, r1, r1, MS, D_MODEL, D_MODEL, false, false);

    // ---- MLP block ----
    ln_kernel<<<MS, 256, 0, stream>>>(r1, mlp_ln_g, mlp_ln_b, lnb);
    gemm(lnb, w1T, mlp_b1, nullptr, hb, MS, DFF, D_MODEL, true, true);
    gemm(hb, w2T, mlp_b2, r1, d_out, MS, D_MODEL, DFF, false, false);
}